// Round 1
// baseline (486.761 us; speedup 1.0000x reference)
//
#include <hip/hip_runtime.h>
#include <cstdint>
#include <cstddef>

typedef short short8 __attribute__((ext_vector_type(8)));
typedef float floatx4 __attribute__((ext_vector_type(4)));
typedef unsigned short ushort4v __attribute__((ext_vector_type(4)));
typedef unsigned short ushort2v __attribute__((ext_vector_type(2)));

#define AS1C(p) ((const __attribute__((address_space(1))) void*)(p))
#define AS3(p)  ((__attribute__((address_space(3))) void*)(p))

// round-to-nearest-even float -> bf16 bits
__device__ __forceinline__ unsigned short f2bf(float f) {
    union { float f; unsigned int u; } v; v.f = f;
    unsigned int u = v.u;
    unsigned int r = (u + 0x7fffu + ((u >> 16) & 1u)) >> 16;
    return (unsigned short)r;
}

__device__ __forceinline__ float wave_sum(float s) {
#pragma unroll
    for (int off = 32; off > 0; off >>= 1)
        s += __shfl_xor(s, off, 64);
    return s;
}

// ---------------------------------------------------------------------------
// Kernel 1: per-row l2norm of feats -> fb (bf16); store rnorm[i]; histogram
// labels with ONE int atomic per row. One wave per row of D=512.
// (The old version did 512 fp32 device-scope atomicAdds per row = 33.5M total;
//  that scatter is replaced by the sort+gather pipeline below.)
// ---------------------------------------------------------------------------
__global__ __launch_bounds__(256) void k_norm(
    const float* __restrict__ feats, const int* __restrict__ labels,
    unsigned short* __restrict__ fb, float* __restrict__ rnorm,
    int* __restrict__ cnt, int N)
{
    const int gw   = (int)((blockIdx.x * 256u + threadIdx.x) >> 6);
    const int lane = threadIdx.x & 63;
    if (gw >= N) return;

    const float* row = feats + (size_t)gw * 512;
    floatx4 x0 = *(const floatx4*)(row + lane * 4);
    floatx4 x1 = *(const floatx4*)(row + 256 + lane * 4);

    float s = x0.x * x0.x + x0.y * x0.y + x0.z * x0.z + x0.w * x0.w
            + x1.x * x1.x + x1.y * x1.y + x1.z * x1.z + x1.w * x1.w;
    s = wave_sum(s);
    const float inv = 1.0f / fmaxf(sqrtf(s), 1e-12f);

    floatx4 y0 = x0 * inv, y1 = x1 * inv;

    ushort4v b0, b1;
    b0.x = f2bf(y0.x); b0.y = f2bf(y0.y); b0.z = f2bf(y0.z); b0.w = f2bf(y0.w);
    b1.x = f2bf(y1.x); b1.y = f2bf(y1.y); b1.z = f2bf(y1.z); b1.w = f2bf(y1.w);
    *(ushort4v*)(fb + (size_t)gw * 512 + lane * 4)       = b0;
    *(ushort4v*)(fb + (size_t)gw * 512 + 256 + lane * 4) = b1;

    if (lane == 0) {
        rnorm[gw] = inv;
        atomicAdd(cnt + labels[gw], 1);
    }
}

// ---------------------------------------------------------------------------
// Kernel 2: exclusive prefix-sum of cnt[C] -> offs[C]; cursor = offs.
// One block, 256 threads, 4 classes/thread, LDS Hillis-Steele scan.
// ---------------------------------------------------------------------------
__global__ __launch_bounds__(256) void k_scan(
    const int* __restrict__ cnt, int* __restrict__ offs,
    int* __restrict__ cursor, int C)
{
    __shared__ int part[256];
    const int t = threadIdx.x;
    const int base = t * 4;
    int a0 = (base + 0 < C) ? cnt[base + 0] : 0;
    int a1 = (base + 1 < C) ? cnt[base + 1] : 0;
    int a2 = (base + 2 < C) ? cnt[base + 2] : 0;
    int a3 = (base + 3 < C) ? cnt[base + 3] : 0;
    const int s = a0 + a1 + a2 + a3;
    part[t] = s;
    __syncthreads();
#pragma unroll
    for (int off = 1; off < 256; off <<= 1) {
        int v = (t >= off) ? part[t - off] : 0;
        __syncthreads();
        part[t] += v;
        __syncthreads();
    }
    const int excl = part[t] - s;
    const int o0 = excl, o1 = o0 + a0, o2 = o1 + a1, o3 = o2 + a2;
    if (base + 0 < C) { offs[base + 0] = o0; cursor[base + 0] = o0; }
    if (base + 1 < C) { offs[base + 1] = o1; cursor[base + 1] = o1; }
    if (base + 2 < C) { offs[base + 2] = o2; cursor[base + 2] = o2; }
    if (base + 3 < C) { offs[base + 3] = o3; cursor[base + 3] = o3; }
}

// ---------------------------------------------------------------------------
// Kernel 3: build per-class row-index lists (counting-sort scatter of indices).
// N int atomics total (vs 33.5M fp32 before).
// ---------------------------------------------------------------------------
__global__ __launch_bounds__(256) void k_scatter_idx(
    const int* __restrict__ labels, int* __restrict__ cursor,
    int* __restrict__ idx, int N)
{
    const int i = (int)(blockIdx.x * 256u + threadIdx.x);
    if (i < N) {
        const int lab = labels[i];
        const int pos = atomicAdd(cursor + lab, 1);
        idx[pos] = i;
    }
}

// ---------------------------------------------------------------------------
// Kernel 4: per-class gather segment-sum (fp32, feats*rnorm for full
// precision) fused with EMA update + renorm; write pb (bf16).
// One block per class; thread t owns columns 2t, 2t+1. Row reads are
// coalesced 2KB bursts. Unrolled x4 for 4 loads in flight.
// ---------------------------------------------------------------------------
__global__ __launch_bounds__(256) void k_segsum_update(
    const float* __restrict__ feats, const float* __restrict__ rnorm,
    const int* __restrict__ idx, const int* __restrict__ offs,
    const int* __restrict__ cnt, const float* __restrict__ protos,
    unsigned short* __restrict__ pb)
{
    const int c = blockIdx.x;
    const int t = threadIdx.x;
    const int n = cnt[c];
    const int o = offs[c];

    float a0 = 0.0f, a1 = 0.0f;
    int j = 0;
    for (; j + 4 <= n; j += 4) {
        const int r0 = idx[o + j + 0];
        const int r1 = idx[o + j + 1];
        const int r2 = idx[o + j + 2];
        const int r3 = idx[o + j + 3];
        const float2 v0 = *(const float2*)(feats + (size_t)r0 * 512 + t * 2);
        const float2 v1 = *(const float2*)(feats + (size_t)r1 * 512 + t * 2);
        const float2 v2 = *(const float2*)(feats + (size_t)r2 * 512 + t * 2);
        const float2 v3 = *(const float2*)(feats + (size_t)r3 * 512 + t * 2);
        const float s0 = rnorm[r0], s1 = rnorm[r1], s2 = rnorm[r2], s3 = rnorm[r3];
        a0 += v0.x * s0 + v1.x * s1 + v2.x * s2 + v3.x * s3;
        a1 += v0.y * s0 + v1.y * s1 + v2.y * s2 + v3.y * s3;
    }
    for (; j < n; ++j) {
        const int r = idx[o + j];
        const float2 v = *(const float2*)(feats + (size_t)r * 512 + t * 2);
        const float sc = rnorm[r];
        a0 += v.x * sc;
        a1 += v.y * sc;
    }

    const float2 p = *(const float2*)(protos + (size_t)c * 512 + t * 2);
    const float rc = 0.1f / fmaxf((float)n, 1.0f);
    const float v0 = 0.9f * p.x + rc * a0;
    const float v1 = 0.9f * p.y + rc * a1;

    __shared__ float red[256];
    red[t] = v0 * v0 + v1 * v1;
    __syncthreads();
#pragma unroll
    for (int off = 128; off > 0; off >>= 1) {
        if (t < off) red[t] += red[t + off];
        __syncthreads();
    }
    const float inv = 1.0f / fmaxf(sqrtf(red[0]), 1e-12f);

    float o0, o1;
    if (n > 0) { o0 = v0 * inv; o1 = v1 * inv; }
    else       { o0 = p.x;      o1 = p.y;      }

    ushort2v b;
    b.x = f2bf(o0);
    b.y = f2bf(o1);
    *(ushort2v*)(pb + (size_t)c * 512 + t * 2) = b;
}

// ---------------------------------------------------------------------------
// Kernel 5: sim[N,C] = f[N,K] @ P[C,K]^T, bf16 inputs, fp32 out.
// m97-style: 128x128 tile, BK=64, 16x16x32 bf16 MFMA, global_load_lds x16.
// Block = 256 threads = 4 waves in 2x2; each wave does 64x64 (4x4 MFMA tiles).
// (unchanged from the verified 832.8 µs version)
// ---------------------------------------------------------------------------
__global__ __launch_bounds__(256, 2) void k_gemm(
    const unsigned short* __restrict__ A, const unsigned short* __restrict__ B,
    float* __restrict__ out, int N, int C, int K)
{
    __shared__ unsigned short As[128 * 64];  // 16 KB, row-major [128][64]
    __shared__ unsigned short Bs[128 * 64];  // 16 KB

    const int tid   = threadIdx.x;
    const int lane  = tid & 63;
    const int wv    = tid >> 6;
    const int waveM = wv >> 1, waveN = wv & 1;
    const int quad  = lane >> 4, l16 = lane & 15;
    const size_t m0 = (size_t)blockIdx.y * 128;
    const size_t n0 = (size_t)blockIdx.x * 128;

    floatx4 zero = {0.0f, 0.0f, 0.0f, 0.0f};
    floatx4 acc[4][4];
#pragma unroll
    for (int i = 0; i < 4; ++i)
#pragma unroll
        for (int j = 0; j < 4; ++j) acc[i][j] = zero;

    const int arow = tid >> 3;        // 0..31  (row within a 32-row staging slab)
    const int kc8  = (tid & 7) * 8;   // k-chunk offset in elements

    for (int k0 = 0; k0 < K; k0 += 64) {
#pragma unroll
        for (int t = 0; t < 4; ++t) {
            const unsigned short* ga = A + (m0 + (size_t)(t * 32 + arow)) * K + (k0 + kc8);
            __builtin_amdgcn_global_load_lds(AS1C(ga), AS3(As + (t * 256 + tid) * 8), 16, 0, 0);
        }
#pragma unroll
        for (int t = 0; t < 4; ++t) {
            const unsigned short* gb = B + (n0 + (size_t)(t * 32 + arow)) * K + (k0 + kc8);
            __builtin_amdgcn_global_load_lds(AS1C(gb), AS3(Bs + (t * 256 + tid) * 8), 16, 0, 0);
        }
        __builtin_amdgcn_s_waitcnt(0);   // drain vmcnt before barrier
        __syncthreads();

#pragma unroll
        for (int s = 0; s < 2; ++s) {    // two K=32 MFMA steps per BK=64
            short8 af[4], bfr[4];
#pragma unroll
            for (int m = 0; m < 4; ++m)
                af[m] = *(const short8*)(As + (waveM * 64 + m * 16 + l16) * 64 + s * 32 + quad * 8);
#pragma unroll
            for (int n = 0; n < 4; ++n)
                bfr[n] = *(const short8*)(Bs + (waveN * 64 + n * 16 + l16) * 64 + s * 32 + quad * 8);
#pragma unroll
            for (int m = 0; m < 4; ++m)
#pragma unroll
                for (int n = 0; n < 4; ++n)
                    acc[m][n] = __builtin_amdgcn_mfma_f32_16x16x32_bf16(af[m], bfr[n], acc[m][n], 0, 0, 0);
        }
        __syncthreads();
    }

    // epilogue: C/D layout col=lane&15, row=(lane>>4)*4+reg
#pragma unroll
    for (int m = 0; m < 4; ++m) {
        const size_t r0 = m0 + (size_t)(waveM * 64 + m * 16 + quad * 4);
#pragma unroll
        for (int n = 0; n < 4; ++n) {
            const size_t c = n0 + (size_t)(waveN * 64 + n * 16 + l16);
#pragma unroll
            for (int r = 0; r < 4; ++r)
                out[(r0 + r) * (size_t)C + c] = acc[m][n][r];
        }
    }
}

// ---------------------------------------------------------------------------
extern "C" void kernel_launch(void* const* d_in, const int* in_sizes, int n_in,
                              void* d_out, int out_size, void* d_ws, size_t ws_size,
                              hipStream_t stream)
{
    const float* feats  = (const float*)d_in[0];
    const float* protos = (const float*)d_in[1];
    const int*   labels = (const int*)d_in[2];
    float* sim = (float*)d_out;

    const int D = 512;
    const int N = in_sizes[0] / D;   // 65536
    const int C = in_sizes[1] / D;   // 1024

    char* w = (char*)d_ws;
    unsigned short* fb = (unsigned short*)w;                 // N*D bf16 = 64 MB
    size_t off = (size_t)N * D * 2;
    unsigned short* pb = (unsigned short*)(w + off);         // C*D bf16 = 1 MB
    off += (size_t)C * D * 2;
    float* rnorm = (float*)(w + off);                        // N f32 = 256 KB
    off += (size_t)N * 4;
    int* idx = (int*)(w + off);                              // N i32 = 256 KB
    off += (size_t)N * 4;
    int* cnt = (int*)(w + off);                              // C i32
    off += (size_t)C * 4;
    int* offs = (int*)(w + off);                             // C i32
    off += (size_t)C * 4;
    int* cursor = (int*)(w + off);                           // C i32

    // only cnt needs zeroing (ws is poisoned 0xAA before every launch);
    // offs/cursor/idx are fully written before first read.
    hipMemsetAsync(cnt, 0, (size_t)C * 4, stream);

    k_norm<<<dim3(N / 4), dim3(256), 0, stream>>>(feats, labels, fb, rnorm, cnt, N);
    k_scan<<<dim3(1), dim3(256), 0, stream>>>(cnt, offs, cursor, C);
    k_scatter_idx<<<dim3(N / 256), dim3(256), 0, stream>>>(labels, cursor, idx, N);
    k_segsum_update<<<dim3(C), dim3(256), 0, stream>>>(feats, rnorm, idx, offs, cnt, protos, pb);

    dim3 g(C / 128, N / 128);   // (8, 512)
    k_gemm<<<g, dim3(256), 0, stream>>>(fb, pb, sim, N, C, D);
}